// Round 1
// baseline (327.139 us; speedup 1.0000x reference)
//
#include <hip/hip_runtime.h>
#include <cstdint>
#include <cstddef>

// Problem dims
#define MDIM 4096   // batch
#define NDIM 4096   // out features
#define KDIM 4096   // in features

typedef _Float16 half8  __attribute__((ext_vector_type(8)));
typedef _Float16 half4v __attribute__((ext_vector_type(4)));
typedef float    floatx4 __attribute__((ext_vector_type(4)));

// Hamilton product tables: out_comp = sum_c sign[comp][c] * (x_c @ W_{q[comp][c]}^T)
// out_r = x0 W0 - x1 W1 - x2 W2 - x3 W3
// out_i = x0 W1 + x1 W0 + x2 W3 - x3 W2
// out_j = x0 W2 - x1 W3 + x2 W0 + x3 W1
// out_k = x0 W3 + x1 W2 - x2 W1 + x3 W0
__device__ __constant__ int   d_qtab[16] = {0,1,2,3,  1,0,3,2,  2,3,0,1,  3,2,1,0};
__device__ __constant__ float d_stab[16] = {1.f,-1.f,-1.f,-1.f,
                                            1.f, 1.f, 1.f,-1.f,
                                            1.f,-1.f, 1.f, 1.f,
                                            1.f, 1.f,-1.f, 1.f};

// ---------------- pre-pass kernels ----------------

// cast x (fp32 [4096,4096]) -> fp16, 4 elems/thread
__global__ void cast_x_kernel(const float* __restrict__ x, _Float16* __restrict__ xh) {
    int idx = blockIdx.x * 256 + threadIdx.x;          // 0 .. 4M-1
    const float4 v = ((const float4*)x)[idx];
    half4v h = {(_Float16)v.x, (_Float16)v.y, (_Float16)v.z, (_Float16)v.w};
    ((half4v*)xh)[idx] = h;
}

// build W_big fp16 [NDIM, KDIM]: row n = out feature (comp*1024+o), col k = c*1024+i
__global__ void pack_w_kernel(const float* __restrict__ W0, const float* __restrict__ W1,
                              const float* __restrict__ W2, const float* __restrict__ W3,
                              _Float16* __restrict__ Wb) {
    int idx = blockIdx.x * 256 + threadIdx.x;          // 0 .. 4M-1
    int e = idx << 2;                                   // element index in W_big
    int n = e >> 12;                                    // out feature
    int k = e & (KDIM - 1);
    int comp = n >> 10;
    int c = k >> 10;
    int t = comp * 4 + c;
    const float* Ws[4] = {W0, W1, W2, W3};
    const float* src = Ws[d_qtab[t]] + (size_t)(n & 1023) * 1024 + (k & 1023);
    float s = d_stab[t];
    const float4 v = *(const float4*)src;
    half4v h = {(_Float16)(s * v.x), (_Float16)(s * v.y),
                (_Float16)(s * v.z), (_Float16)(s * v.w)};
    *(half4v*)(Wb + e) = h;
}

// bias_big[n] = sum_c sign[comp][c] * b_{q[comp][c]}[o]
__global__ void pack_bias_kernel(const float* __restrict__ b0, const float* __restrict__ b1,
                                 const float* __restrict__ b2, const float* __restrict__ b3,
                                 float* __restrict__ bias) {
    int n = blockIdx.x * 256 + threadIdx.x;            // 0..4095
    int comp = n >> 10, o = n & 1023;
    const float* bs[4] = {b0, b1, b2, b3};
    float v = 0.f;
#pragma unroll
    for (int c = 0; c < 4; c++)
        v += d_stab[comp * 4 + c] * bs[d_qtab[comp * 4 + c]][o];
    bias[n] = v;
}

// ---------------- MFMA GEMM ----------------
// C[M,N] = A[M,K] * Wb[N,K]^T + bias[N]; A,Wb fp16, C fp32.
// Block: 256 threads (4 waves), tile 128x128, BK=32.
// Wave w -> 64x64 subtile at (wm, wn); 4x4 grid of 16x16x32 MFMAs.

__device__ __forceinline__ void gload_lds16(const _Float16* g, _Float16* l) {
    __builtin_amdgcn_global_load_lds(
        (const __attribute__((address_space(1))) unsigned int*)g,
        (__attribute__((address_space(3))) unsigned int*)l,
        16, 0, 0);
}

__global__ __launch_bounds__(256) void gemm_kernel(const _Float16* __restrict__ A,
                                                   const _Float16* __restrict__ B,
                                                   const float* __restrict__ bias,
                                                   float* __restrict__ C) {
    __shared__ _Float16 As[128 * 32];   // 8 KB, row-major [row][k], no pad (global_load_lds)
    __shared__ _Float16 Bs[128 * 32];   // 8 KB

    const int tid  = threadIdx.x;
    const int lane = tid & 63;
    const int wave = tid >> 6;
    const int wm = (wave & 1) * 64;
    const int wn = (wave >> 1) * 64;

    const int bm = blockIdx.x & 31;
    const int bn = blockIdx.x >> 5;
    const int m0 = bm * 128;
    const int n0 = bn * 128;

    // staging: thread tid loads 16B: row = tid/4, k-chunk = (tid%4)*8 ; chunk1 = +64 rows
    const int srow = tid >> 2;
    const int skc  = (tid & 3) * 8;
    const _Float16* Ag0 = A + (size_t)(m0 + srow) * KDIM + skc;
    const _Float16* Bg0 = B + (size_t)(n0 + srow) * KDIM + skc;
    _Float16* Asl0 = As + tid * 8;
    _Float16* Asl1 = As + 2048 + tid * 8;
    _Float16* Bsl0 = Bs + tid * 8;
    _Float16* Bsl1 = Bs + 2048 + tid * 8;

    floatx4 acc[4][4];
#pragma unroll
    for (int i = 0; i < 4; i++)
#pragma unroll
        for (int j = 0; j < 4; j++)
            acc[i][j] = (floatx4){0.f, 0.f, 0.f, 0.f};

    const int fr = lane & 15;            // row (A) / col (B) within 16
    const int fq = (lane >> 4) * 8;      // k offset of the 8-elem fragment

    for (int k0 = 0; k0 < KDIM; k0 += 32) {
        gload_lds16(Ag0 + k0, Asl0);
        gload_lds16(Ag0 + (size_t)64 * KDIM + k0, Asl1);
        gload_lds16(Bg0 + k0, Bsl0);
        gload_lds16(Bg0 + (size_t)64 * KDIM + k0, Bsl1);
        __syncthreads();                 // waits vmcnt(0): LDS-DMA complete

        half8 af[4], bf[4];
#pragma unroll
        for (int i = 0; i < 4; i++) {
            af[i] = *(const half8*)(As + (wm + i * 16 + fr) * 32 + fq);
            bf[i] = *(const half8*)(Bs + (wn + i * 16 + fr) * 32 + fq);
        }
#pragma unroll
        for (int i = 0; i < 4; i++)
#pragma unroll
            for (int j = 0; j < 4; j++)
                acc[i][j] = __builtin_amdgcn_mfma_f32_16x16x32_f16(af[i], bf[j], acc[i][j], 0, 0, 0);

        __syncthreads();                 // protect LDS before next stage
    }

    // Epilogue: D[row][col], col = lane&15, row = (lane>>4)*4 + r  [m89 layout]
    const int col   = lane & 15;
    const int rquad = (lane >> 4) * 4;
#pragma unroll
    for (int j = 0; j < 4; j++) {
        const int gn = n0 + wn + j * 16 + col;
        const float bv = bias[gn];
#pragma unroll
        for (int i = 0; i < 4; i++) {
            const int gmb = m0 + wm + i * 16 + rquad;
#pragma unroll
            for (int r = 0; r < 4; r++)
                C[(size_t)(gmb + r) * NDIM + gn] = acc[i][j][r] + bv;
        }
    }
}

// ---------------- fp32 fallback (only if ws too small) ----------------
__global__ void fallback_kernel(const float* __restrict__ x,
                                const float* __restrict__ W0, const float* __restrict__ W1,
                                const float* __restrict__ W2, const float* __restrict__ W3,
                                const float* __restrict__ b0, const float* __restrict__ b1,
                                const float* __restrict__ b2, const float* __restrict__ b3,
                                float* __restrict__ out) {
    int idx = blockIdx.x * 256 + threadIdx.x;   // 16M outputs
    int m = idx >> 12, n = idx & 4095;
    int comp = n >> 10, o = n & 1023;
    const float* Ws[4] = {W0, W1, W2, W3};
    const float* bs[4] = {b0, b1, b2, b3};
    float acc = 0.f;
    for (int c = 0; c < 4; c++) {
        int t = comp * 4 + c;
        const float* wr = Ws[d_qtab[t]] + (size_t)o * 1024;
        const float* xr = x + (size_t)m * 4096 + c * 1024;
        float s = d_stab[t];
        float dot = 0.f;
        for (int i = 0; i < 1024; i += 4) {
            float4 wv = *(const float4*)(wr + i);
            float4 xv = *(const float4*)(xr + i);
            dot += wv.x * xv.x + wv.y * xv.y + wv.z * xv.z + wv.w * xv.w;
        }
        acc += s * dot + s * bs[d_qtab[t]][o];
    }
    out[idx] = acc;
}

// ---------------- launch ----------------
extern "C" void kernel_launch(void* const* d_in, const int* in_sizes, int n_in,
                              void* d_out, int out_size, void* d_ws, size_t ws_size,
                              hipStream_t stream) {
    const float* x = (const float*)d_in[0];
    const float* W[4];
    const float* b[4];
    int wi = 0, bi = 0;
    for (int i = 1; i < n_in && i < 9; i++) {
        if (in_sizes[i] > 4096) { if (wi < 4) W[wi++] = (const float*)d_in[i]; }
        else                    { if (bi < 4) b[bi++] = (const float*)d_in[i]; }
    }
    float* out = (float*)d_out;

    const size_t xh_elems = (size_t)MDIM * KDIM;       // 16M fp16 = 32 MB
    const size_t wb_elems = (size_t)NDIM * KDIM;       // 16M fp16 = 32 MB
    const size_t needed = xh_elems * 2 + wb_elems * 2 + (size_t)NDIM * 4;

    if (ws_size < needed) {
        // safety net: correct but slow
        fallback_kernel<<<(MDIM * NDIM) / 256, 256, 0, stream>>>(
            x, W[0], W[1], W[2], W[3], b[0], b[1], b[2], b[3], out);
        return;
    }

    _Float16* xh   = (_Float16*)d_ws;
    _Float16* Wb   = xh + xh_elems;
    float*    bigb = (float*)(Wb + wb_elems);

    cast_x_kernel<<<(MDIM * KDIM) / (256 * 4), 256, 0, stream>>>(x, xh);
    pack_w_kernel<<<(NDIM * KDIM) / (256 * 4), 256, 0, stream>>>(W[0], W[1], W[2], W[3], Wb);
    pack_bias_kernel<<<NDIM / 256, 256, 0, stream>>>(b[0], b[1], b[2], b[3], bigb);
    gemm_kernel<<<(MDIM / 128) * (NDIM / 128), 256, 0, stream>>>(xh, Wb, bigb, out);
}

// Round 2
// 298.938 us; speedup vs baseline: 1.0943x; 1.0943x over previous
//
#include <hip/hip_runtime.h>
#include <cstdint>
#include <cstddef>

#define MDIM 4096   // batch
#define NDIM 4096   // out features
#define KDIM 4096   // in features

typedef _Float16 half8  __attribute__((ext_vector_type(8)));
typedef float    floatx4 __attribute__((ext_vector_type(4)));

// Hamilton product tables: out_comp = sum_c sign[comp][c] * (x_c @ W_{q[comp][c]}^T)
__device__ __constant__ int   d_qtab[16] = {0,1,2,3,  1,0,3,2,  2,3,0,1,  3,2,1,0};
__device__ __constant__ float d_stab[16] = {1.f,-1.f,-1.f,-1.f,
                                            1.f, 1.f, 1.f,-1.f,
                                            1.f,-1.f, 1.f, 1.f,
                                            1.f, 1.f,-1.f, 1.f};

// ---------------- pre-pass: fp32 -> fp16 casts ----------------

// cast x [4096,4096] fp32 -> fp16, 8 elems/thread
__global__ void cast_x_kernel(const float* __restrict__ x, _Float16* __restrict__ xh) {
    int idx = blockIdx.x * 256 + threadIdx.x;          // 0 .. 2M-1
    const float4* src = (const float4*)x + (size_t)idx * 2;
    float4 a = src[0], b = src[1];
    half8 h = {(_Float16)a.x, (_Float16)a.y, (_Float16)a.z, (_Float16)a.w,
               (_Float16)b.x, (_Float16)b.y, (_Float16)b.z, (_Float16)b.w};
    ((half8*)xh)[idx] = h;
}

// cast the four 1024x1024 W matrices fp32 -> fp16 into one [4][1024][1024] buffer
__global__ void cast_w_kernel(const float* __restrict__ W0, const float* __restrict__ W1,
                              const float* __restrict__ W2, const float* __restrict__ W3,
                              _Float16* __restrict__ Wh) {
    int idx = blockIdx.x * 256 + threadIdx.x;          // 0 .. 512K-1
    int e = idx << 3;                                   // element index, 0..4M-1
    int m = e >> 20;                                    // which matrix
    const float* Ws[4] = {W0, W1, W2, W3};
    const float* src = Ws[m] + (e & ((1 << 20) - 1));
    float4 a = *(const float4*)src;
    float4 b = *(const float4*)(src + 4);
    half8 h = {(_Float16)a.x, (_Float16)a.y, (_Float16)a.z, (_Float16)a.w,
               (_Float16)b.x, (_Float16)b.y, (_Float16)b.z, (_Float16)b.w};
    *(half8*)(Wh + e) = h;
}

// ---------------- MFMA GEMM ----------------
// C[M,N] = A[M,K] * W_big[N,K]^T + bias[N], where W_big rows come straight
// from the four W matrices with a wave-uniform sign per (comp, c-phase),
// applied to the A fragments. A, W fp16; C fp32.
// Block: 256 threads (4 waves), tile 128x128, BK=32, single-buffered LDS.

__device__ __forceinline__ void gload_lds16(const _Float16* g, _Float16* l) {
    __builtin_amdgcn_global_load_lds(
        (const __attribute__((address_space(1))) unsigned int*)g,
        (__attribute__((address_space(3))) unsigned int*)l,
        16, 0, 0);
}

__global__ __launch_bounds__(256, 4) void gemm_kernel(
        const _Float16* __restrict__ A,      // [4096,4096] fp16
        const _Float16* __restrict__ Wh,     // [4][1024][1024] fp16
        const float* __restrict__ b0, const float* __restrict__ b1,
        const float* __restrict__ b2, const float* __restrict__ b3,
        float* __restrict__ C) {
    __shared__ _Float16 As[128 * 32];   // 8 KB
    __shared__ _Float16 Bs[128 * 32];   // 8 KB

    const int tid  = threadIdx.x;
    const int lane = tid & 63;
    const int wave = tid >> 6;
    const int wm = (wave & 1) * 64;
    const int wn = (wave >> 1) * 64;

    // L2-friendly swizzle: 8 m-tiles per supergroup, n advances inside
    const int g = blockIdx.x;                 // 0..1023 over 32x32 tiles
    const int group_id = g >> 8;              // 0..3
    const int bm = group_id * 8 + (g & 7);
    const int bn = (g & 255) >> 3;
    const int m0 = bm * 128;
    const int n0 = bn * 128;
    const int comp = n0 >> 10;                // output quaternion component (block-uniform)

    // staging: thread tid loads 16B: row = tid>>2, chunk swizzled by row for
    // conflict-free fragment reads: chunk_g = (tid&3) ^ ((row>>1)&3)
    const int srow = tid >> 2;
    const int skc  = (((tid & 3) ^ ((srow >> 1) & 3))) * 8;   // halves
    const _Float16* Ag0 = A + (size_t)(m0 + srow) * KDIM + skc;
    const int brow = (n0 & 1023) + srow;      // row within the 1024-row W matrix

    _Float16* Asl0 = As + tid * 8;
    _Float16* Asl1 = As + 2048 + tid * 8;     // rows 64..127 (same skc: (row+64)>>1 ≡ row>>1 mod 4)
    _Float16* Bsl0 = Bs + tid * 8;
    _Float16* Bsl1 = Bs + 2048 + tid * 8;

    floatx4 acc[4][4];
#pragma unroll
    for (int i = 0; i < 4; i++)
#pragma unroll
        for (int j = 0; j < 4; j++)
            acc[i][j] = (floatx4){0.f, 0.f, 0.f, 0.f};

    const int fr = lane & 15;                 // row (A) / col (B) within 16
    const int q  = lane >> 4;                 // k-chunk 0..3
    const int slot8 = (q ^ ((fr >> 1) & 3)) * 8;   // swizzled LDS chunk offset (halves)

    for (int c = 0; c < 4; c++) {
        const int t = comp * 4 + c;
        const _Float16* Bg0 = Wh + ((size_t)d_qtab[t] << 20) + (size_t)brow * 1024 + skc;
        const _Float16* Ag  = Ag0 + c * 1024;
        const _Float16 s = (_Float16)d_stab[t];
        half8 sv = {s, s, s, s, s, s, s, s};

        for (int kk = 0; kk < 1024; kk += 32) {
            gload_lds16(Ag + kk, Asl0);
            gload_lds16(Ag + (size_t)64 * KDIM + kk, Asl1);
            gload_lds16(Bg0 + kk, Bsl0);
            gload_lds16(Bg0 + (size_t)64 * 1024 + kk, Bsl1);
            __syncthreads();

            half8 af[4], bf[4];
#pragma unroll
            for (int i = 0; i < 4; i++) {
                af[i] = *(const half8*)(As + (wm + i * 16 + fr) * 32 + slot8) * sv;
                bf[i] = *(const half8*)(Bs + (wn + i * 16 + fr) * 32 + slot8);
            }
#pragma unroll
            for (int i = 0; i < 4; i++)
#pragma unroll
                for (int j = 0; j < 4; j++)
                    acc[i][j] = __builtin_amdgcn_mfma_f32_16x16x32_f16(af[i], bf[j], acc[i][j], 0, 0, 0);

            __syncthreads();
        }
    }

    // Epilogue: D[row][col], col = lane&15, row = (lane>>4)*4 + r  [m89 layout]
    const int col   = lane & 15;
    const int rquad = (lane >> 4) * 4;
    const float* bs[4] = {b0, b1, b2, b3};
#pragma unroll
    for (int j = 0; j < 4; j++) {
        const int gn = n0 + wn + j * 16 + col;
        const int o  = gn & 1023;
        float bv = 0.f;
#pragma unroll
        for (int c = 0; c < 4; c++)
            bv += d_stab[comp * 4 + c] * bs[d_qtab[comp * 4 + c]][o];
#pragma unroll
        for (int i = 0; i < 4; i++) {
            const int gmb = m0 + wm + i * 16 + rquad;
#pragma unroll
            for (int r = 0; r < 4; r++)
                C[(size_t)(gmb + r) * NDIM + gn] = acc[i][j][r] + bv;
        }
    }
}

// ---------------- fp32 fallback (only if ws too small) ----------------
__global__ void fallback_kernel(const float* __restrict__ x,
                                const float* __restrict__ W0, const float* __restrict__ W1,
                                const float* __restrict__ W2, const float* __restrict__ W3,
                                const float* __restrict__ b0, const float* __restrict__ b1,
                                const float* __restrict__ b2, const float* __restrict__ b3,
                                float* __restrict__ out) {
    int idx = blockIdx.x * 256 + threadIdx.x;   // 16M outputs
    int m = idx >> 12, n = idx & 4095;
    int comp = n >> 10, o = n & 1023;
    const float* Ws[4] = {W0, W1, W2, W3};
    const float* bs[4] = {b0, b1, b2, b3};
    float acc = 0.f;
    for (int c = 0; c < 4; c++) {
        int t = comp * 4 + c;
        const float* wr = Ws[d_qtab[t]] + (size_t)o * 1024;
        const float* xr = x + (size_t)m * 4096 + c * 1024;
        float s = d_stab[t];
        float dot = 0.f;
        for (int i = 0; i < 1024; i += 4) {
            float4 wv = *(const float4*)(wr + i);
            float4 xv = *(const float4*)(xr + i);
            dot += wv.x * xv.x + wv.y * xv.y + wv.z * xv.z + wv.w * xv.w;
        }
        acc += s * dot + s * bs[d_qtab[t]][o];
    }
    out[idx] = acc;
}

// ---------------- launch ----------------
extern "C" void kernel_launch(void* const* d_in, const int* in_sizes, int n_in,
                              void* d_out, int out_size, void* d_ws, size_t ws_size,
                              hipStream_t stream) {
    const float* x = (const float*)d_in[0];
    const float* W[4];
    const float* b[4];
    int wi = 0, bi = 0;
    for (int i = 1; i < n_in && i < 9; i++) {
        if (in_sizes[i] > 4096) { if (wi < 4) W[wi++] = (const float*)d_in[i]; }
        else                    { if (bi < 4) b[bi++] = (const float*)d_in[i]; }
    }
    float* out = (float*)d_out;

    const size_t xh_elems = (size_t)MDIM * KDIM;        // 16M fp16 = 32 MB
    const size_t wh_elems = (size_t)4 * 1024 * 1024;    // 4M fp16 = 8 MB
    const size_t needed = (xh_elems + wh_elems) * 2;

    if (ws_size < needed) {
        fallback_kernel<<<(MDIM * NDIM) / 256, 256, 0, stream>>>(
            x, W[0], W[1], W[2], W[3], b[0], b[1], b[2], b[3], out);
        return;
    }

    _Float16* xh = (_Float16*)d_ws;
    _Float16* Wh = xh + xh_elems;

    cast_x_kernel<<<(MDIM * KDIM) / (256 * 8), 256, 0, stream>>>(x, xh);
    cast_w_kernel<<<(4 * 1024 * 1024) / (256 * 8), 256, 0, stream>>>(W[0], W[1], W[2], W[3], Wh);
    gemm_kernel<<<(MDIM / 128) * (NDIM / 128), 256, 0, stream>>>(
        xh, Wh, b[0], b[1], b[2], b[3], out);
}